// Round 4
// baseline (205.119 us; speedup 1.0000x reference)
//
#include <hip/hip_runtime.h>
#include <hip/hip_bf16.h>

typedef __hip_bfloat16 bf16;
typedef __attribute__((ext_vector_type(8))) short short8v;   // bf16x8 MFMA fragment
typedef __attribute__((ext_vector_type(4))) float f32x4;     // MFMA accumulator

#define NB   32
#define NTT  512
#define NJ   17
#define ND   128
#define NP   6
#define NH   4
#define NDH  32
#define NBT  (NB*NTT)        // 16384 frames
#define NG   4               // frames per block
#define NTOK (NG*NP)         // 24 tokens per block
#define NMT  2               // M-tiles (24 rows -> 2x16, 8 pad rows)
#define NTHR 512             // 8 waves
#define TSTR 136             // bf16 row stride: 272B, 16B-aligned
#define QKSTR 272            // q|k row stride (bf16): 544B, 16B-aligned
#define YSTR 132             // y fp32 row stride: 528B, 16B-aligned

// ws layout (bf16): [0,16384) W_proj | [16384,65536) W_in | [65536,81920) W_out
#define WS_WP 0
#define WS_WI 16384
#define WS_WO 65536

__constant__ int c_pidx[NP][5] = {{0,1,2,3,4},{5,6,11,12,0},{5,7,9,0,0},
                                  {6,8,10,0,0},{11,13,15,0,0},{12,14,16,0,0}};
__constant__ int c_plen[NP] = {5,4,3,3,3,3};

__device__ __forceinline__ float bf2f(unsigned short u) {
    return __uint_as_float(((unsigned)u) << 16);
}
__device__ __forceinline__ f32x4 MFMA(short8v a, short8v b, f32x4 c) {
    return __builtin_amdgcn_mfma_f32_16x16x32_bf16(a, b, c, 0, 0, 0);
}
// B-fragment from bf16 weight (row-major [dout][k] == B^T): one 16B load.
__device__ __forceinline__ short8v ldB(const bf16* __restrict__ W, int nt, int ks, int lane) {
    return *reinterpret_cast<const short8v*>(W + (nt*16 + (lane & 15))*ND + ks*32 + ((lane >> 4) << 3));
}
// A-fragment from bf16 LDS tile with row stride `str`. Rows >= NTOK read garbage
// within the buffer (strides keep it in-bounds) and are discarded on store.
__device__ __forceinline__ short8v ldsA(const bf16* __restrict__ s, int str, int mt, int ks, int lane) {
    int row = mt*16 + (lane & 15);
    if (row >= NTOK) row = NTOK - 1;           // stay in-bounds; result unused
    return *reinterpret_cast<const short8v*>(s + row*str + ks*32 + ((lane >> 4) << 3));
}

// ---- K0: one-shot fp32 -> bf16 weight conversion into d_ws ----
extern "C" __global__ __launch_bounds__(256)
void wconv(const float* __restrict__ Wp, const float* __restrict__ Wi,
           const float* __restrict__ Wo, bf16* __restrict__ ws) {
    int i = blockIdx.x*256 + threadIdx.x;     // 81920 total
    float v;
    if (i < 16384)      v = Wp[i];
    else if (i < 65536) v = Wi[i - 16384];
    else                v = Wo[i - 65536];
    ws[i] = __float2bfloat16(v);
}

extern "C" __global__ __launch_bounds__(NTHR, 8)
void bpa_fused(const float* __restrict__ h_joint,
               const float* __restrict__ mask_joint,
               const bf16* __restrict__ wgt,
               const float* __restrict__ b_proj, const float* __restrict__ b_in,
               const float* __restrict__ b_out,
               const float* __restrict__ ln_g,  const float* __restrict__ ln_b,
               float* __restrict__ out)
{
    __shared__ __align__(16) bf16 s_pool[NTOK*TSTR];   // pooled tokens; then v
    __shared__ __align__(16) bf16 s_tokp[NTOK*TSTR];   // proj out (A + residual)
    __shared__ __align__(16) bf16 s_qk[NTOK*QKSTR];    // q|k ; o over q; then y fp32
    __shared__ float s_probs[NG*NH*NP*NP];             // 2304 B
    __shared__ float s_mu[NTOK];
    __shared__ float s_inv[NTOK];
    float* s_y = reinterpret_cast<float*>(s_qk);       // [24][YSTR] fp32 (12.7KB <= 13.1KB)

    const int tid  = threadIdx.x;
    const int lane = tid & 63;
    const int w    = tid >> 6;                          // wave 0..7
    const long frame0 = (long)blockIdx.x * NG;

    // Prefetch W_proj B-fragments (tile w) — overlaps with pooling loads.
    short8v bp[4];
    #pragma unroll
    for (int ks = 0; ks < 4; ++ks) bp[ks] = ldB(wgt + WS_WP, w, ks, lane);

    // ---- Stage 1: mask-aware mean pooling -> s_pool (bf16) ----
    #pragma unroll
    for (int i = 0; i < (NTOK*ND)/NTHR; ++i) {   // 6 iters
        int idx = i*NTHR + tid;
        int token = idx >> 7;
        int d = idx & (ND-1);
        int f = token / NP, p = token - f*NP;
        const float* hrow = h_joint + (frame0 + f)*(long)(NJ*ND);
        const float* mrow = mask_joint + (frame0 + f)*(long)NJ;
        int len = c_plen[p];
        float s = 0.f, cnt = 0.f;
        #pragma unroll
        for (int l = 0; l < 5; ++l) {
            int j = c_pidx[p][l];
            float mv = mrow[j];
            bool use = (l < len) && (mv > 0.05f);
            if (use) { s += hrow[j*ND + d]; cnt += 1.f; }
        }
        s_pool[token*TSTR + d] = __float2bfloat16(s / fmaxf(cnt, 1e-6f));
    }
    __syncthreads();

    // ---- Stage 2: proj = pool @ Wp^T + b  (wave w owns N-tile w) ----
    {
        f32x4 acc[NMT];
        acc[0] = (f32x4)(0.f); acc[1] = (f32x4)(0.f);
        #pragma unroll
        for (int ks = 0; ks < 4; ++ks)
            #pragma unroll
            for (int mt = 0; mt < NMT; ++mt)
                acc[mt] = MFMA(ldsA(s_pool, TSTR, mt, ks, lane), bp[ks], acc[mt]);
        int col = w*16 + (lane & 15);
        float bv = b_proj[col];
        #pragma unroll
        for (int mt = 0; mt < NMT; ++mt)
            #pragma unroll
            for (int j = 0; j < 4; ++j) {
                int row = mt*16 + ((lane >> 4) << 2) + j;
                if (row < NTOK)
                    s_tokp[row*TSTR + col] = __float2bfloat16(acc[mt][j] + bv);
            }
    }
    __syncthreads();

    // ---- Stage 3: qkv = tokp @ Win^T + b (wave w owns tiles w, 8+w, 16+w) ----
    #pragma unroll
    for (int t = 0; t < 3; ++t) {
        int nt = t*8 + w;                       // t=0:q, t=1:k, t=2:v
        short8v b[4];
        #pragma unroll
        for (int ks = 0; ks < 4; ++ks) b[ks] = ldB(wgt + WS_WI, nt, ks, lane);
        f32x4 acc[NMT];
        acc[0] = (f32x4)(0.f); acc[1] = (f32x4)(0.f);
        #pragma unroll
        for (int ks = 0; ks < 4; ++ks)
            #pragma unroll
            for (int mt = 0; mt < NMT; ++mt)
                acc[mt] = MFMA(ldsA(s_tokp, TSTR, mt, ks, lane), b[ks], acc[mt]);
        int col = nt*16 + (lane & 15);          // 0..383
        float bv = b_in[col];
        #pragma unroll
        for (int mt = 0; mt < NMT; ++mt)
            #pragma unroll
            for (int j = 0; j < 4; ++j) {
                int row = mt*16 + ((lane >> 4) << 2) + j;
                if (row < NTOK) {
                    float v = acc[mt][j] + bv;
                    if (t < 2) s_qk[row*QKSTR + col] = __float2bfloat16(v);
                    else       s_pool[row*TSTR + (col - 256)] = __float2bfloat16(v);
                }
            }
    }
    __syncthreads();

    // ---- Stage 4: attention scores + softmax -> s_probs ----
    if (tid < NG*NH*NP) {   // 96 threads: (f, h, qi)
        int f   = tid / (NH*NP);
        int rem = tid - f*(NH*NP);
        int h   = rem / NP;
        int qi  = rem - h*NP;
        const bf16* qrow = s_qk + (f*NP+qi)*QKSTR + h*NDH;
        float sc[NP];
        float mx = -1e30f;
        #pragma unroll
        for (int pk = 0; pk < NP; ++pk) {
            const bf16* krow = s_qk + (f*NP+pk)*QKSTR + ND + h*NDH;
            float s = 0.f;
            #pragma unroll
            for (int c = 0; c < NDH; c += 4) {
                ushort4 uq = *reinterpret_cast<const ushort4*>(qrow + c);
                ushort4 uk = *reinterpret_cast<const ushort4*>(krow + c);
                s += bf2f(uq.x)*bf2f(uk.x) + bf2f(uq.y)*bf2f(uk.y)
                   + bf2f(uq.z)*bf2f(uk.z) + bf2f(uq.w)*bf2f(uk.w);
            }
            sc[pk] = s * 0.17677669529663688f;   // 1/sqrt(32)
            mx = fmaxf(mx, sc[pk]);
        }
        float den = 0.f, e[NP];
        #pragma unroll
        for (int pk = 0; pk < NP; ++pk) { e[pk] = expf(sc[pk]-mx); den += e[pk]; }
        float inv = 1.f/den;
        #pragma unroll
        for (int pk = 0; pk < NP; ++pk)
            s_probs[((f*NH+h)*NP+qi)*NP + pk] = e[pk]*inv;
    }
    __syncthreads();

    // ---- Stage 5: part_importance + o = w @ v (o over q region of s_qk) ----
    if (tid < NG*NP) {  // 24 threads: (f, pk)
        int f = tid / NP, pk = tid - f*NP;
        float s = 0.f;
        #pragma unroll
        for (int h = 0; h < NH; ++h)
            #pragma unroll
            for (int q = 0; q < NP; ++q)
                s += s_probs[((f*NH+h)*NP+q)*NP + pk];
        out[(long)NBT*NP*ND + (frame0+f)*NP + pk] = s * (1.f/24.f);
    }
    #pragma unroll
    for (int i = 0; i < (NTOK*ND)/NTHR; ++i) {   // 6 iters
        int idx = i*NTHR + tid;
        int token = idx >> 7;
        int d = idx & (ND-1);
        int f = token / NP, qi = token - f*NP;
        int h = d >> 5;
        const float* pr = s_probs + ((f*NH+h)*NP+qi)*NP;
        float s = 0.f;
        #pragma unroll
        for (int pk = 0; pk < NP; ++pk) {
            float v = bf2f(reinterpret_cast<const unsigned short*>(s_pool)[(f*NP+pk)*TSTR + d]);
            s += pr[pk]*v;
        }
        s_qk[token*QKSTR + d] = __float2bfloat16(s);   // o over dead q
    }
    __syncthreads();

    // ---- Stage 6: y = o @ Wout^T + b + resid -> fp32 y (aliases s_qk) ----
    {
        short8v bo[4];
        #pragma unroll
        for (int ks = 0; ks < 4; ++ks) bo[ks] = ldB(wgt + WS_WO, w, ks, lane);
        f32x4 acc[NMT];
        acc[0] = (f32x4)(0.f); acc[1] = (f32x4)(0.f);
        #pragma unroll
        for (int ks = 0; ks < 4; ++ks)
            #pragma unroll
            for (int mt = 0; mt < NMT; ++mt)
                acc[mt] = MFMA(ldsA(s_qk, QKSTR, mt, ks, lane), bo[ks], acc[mt]);
        __syncthreads();   // all o reads done before y overwrites the region
        int col = w*16 + (lane & 15);
        float bv = b_out[col];
        #pragma unroll
        for (int mt = 0; mt < NMT; ++mt)
            #pragma unroll
            for (int j = 0; j < 4; ++j) {
                int row = mt*16 + ((lane >> 4) << 2) + j;
                if (row < NTOK) {
                    float resid = bf2f(*reinterpret_cast<const unsigned short*>(&s_tokp[row*TSTR + col]));
                    s_y[row*YSTR + col] = acc[mt][j] + bv + resid;
                }
            }
    }
    __syncthreads();

    // ---- Stage 7: LayerNorm stats (4 lanes per token) ----
    if (tid < NTOK*4) {   // 96 threads
        int token = tid >> 2, sub = tid & 3;
        const float* row = s_y + token*YSTR + sub*NDH;
        float s = 0.f, s2 = 0.f;
        #pragma unroll
        for (int j = 0; j < NDH; j += 4) {
            float4 v = *reinterpret_cast<const float4*>(row + j);
            s  += v.x + v.y + v.z + v.w;
            s2 += v.x*v.x + v.y*v.y + v.z*v.z + v.w*v.w;
        }
        s  += __shfl_xor(s, 1);  s  += __shfl_xor(s, 2);
        s2 += __shfl_xor(s2, 1); s2 += __shfl_xor(s2, 2);
        float mean = s * (1.f/128.f);
        float var  = s2 * (1.f/128.f) - mean*mean;
        if (sub == 0) {
            s_mu[token]  = mean;
            s_inv[token] = rsqrtf(var + 1e-5f);
        }
    }
    __syncthreads();

    // ---- Stage 8: normalize + coalesced store (768 float4, 512 threads) ----
    #pragma unroll
    for (int i = 0; i < 2; ++i) {
        int idx4 = i*NTHR + tid;
        if (idx4 < NTOK*(ND/4)) {
            int token = idx4 >> 5;
            int dj = (idx4 & 31) << 2;
            float mean = s_mu[token], inv = s_inv[token];
            float4 v = *reinterpret_cast<const float4*>(s_y + token*YSTR + dj);
            float4 g = *reinterpret_cast<const float4*>(ln_g + dj);
            float4 b = *reinterpret_cast<const float4*>(ln_b + dj);
            float4 r;
            r.x = (v.x-mean)*inv*g.x + b.x;
            r.y = (v.y-mean)*inv*g.y + b.y;
            r.z = (v.z-mean)*inv*g.z + b.z;
            r.w = (v.w-mean)*inv*g.w + b.w;
            *reinterpret_cast<float4*>(out + (frame0*NP + token)*(long)ND + dj) = r;
        }
    }
}

extern "C" void kernel_launch(void* const* d_in, const int* in_sizes, int n_in,
                              void* d_out, int out_size, void* d_ws, size_t ws_size,
                              hipStream_t stream) {
    const float* h_joint = (const float*)d_in[0];
    const float* mask    = (const float*)d_in[1];
    const float* W_proj  = (const float*)d_in[2];
    const float* b_proj  = (const float*)d_in[3];
    const float* W_in    = (const float*)d_in[4];
    const float* b_in    = (const float*)d_in[5];
    const float* W_out   = (const float*)d_in[6];
    const float* b_out   = (const float*)d_in[7];
    const float* ln_g    = (const float*)d_in[8];
    const float* ln_b    = (const float*)d_in[9];
    float* out = (float*)d_out;
    bf16* wgt = (bf16*)d_ws;                     // 81920 bf16 = 160 KB

    hipLaunchKernelGGL(wconv, dim3(81920/256), dim3(256), 0, stream,
                       W_proj, W_in, W_out, wgt);
    hipLaunchKernelGGL(bpa_fused, dim3(NBT/NG), dim3(NTHR), 0, stream,
                       h_joint, mask, wgt, b_proj, b_in, b_out, ln_g, ln_b, out);
}

// Round 5
// 107.258 us; speedup vs baseline: 1.9124x; 1.9124x over previous
//
#include <hip/hip_runtime.h>
#include <hip/hip_bf16.h>

typedef __hip_bfloat16 bf16;
typedef __attribute__((ext_vector_type(8))) short short8v;   // bf16x8 MFMA fragment
typedef __attribute__((ext_vector_type(4))) float f32x4;     // MFMA accumulator

#define NB   32
#define NTT  512
#define NJ   17
#define ND   128
#define NP   6
#define NH   4
#define NDH  32
#define NBT  (NB*NTT)        // 16384 frames
#define NG   4               // frames per block
#define NTOK (NG*NP)         // 24 tokens per block
#define NMT  2               // M-tiles (24 rows -> 2x16, 8 pad rows)
#define NTHR 512             // 8 waves
#define TSTR 136             // bf16 row stride: 272B, 16B-aligned
#define QKSTR 272            // q|k row stride (bf16): 544B, 16B-aligned
#define YSTR 132             // y fp32 row stride: 528B, 16B-aligned

// ws layout (bf16): [0,16384) W_proj | [16384,65536) W_in | [65536,81920) W_out
#define WS_WP 0
#define WS_WI 16384
#define WS_WO 65536

__device__ __forceinline__ float bf2f(unsigned short u) {
    return __uint_as_float(((unsigned)u) << 16);
}
__device__ __forceinline__ f32x4 MFMA(short8v a, short8v b, f32x4 c) {
    return __builtin_amdgcn_mfma_f32_16x16x32_bf16(a, b, c, 0, 0, 0);
}
// B-fragment from bf16 weight (row-major [dout][k] == B^T): one 16B load.
__device__ __forceinline__ short8v ldB(const bf16* __restrict__ W, int nt, int ks, int lane) {
    return *reinterpret_cast<const short8v*>(W + (nt*16 + (lane & 15))*ND + ks*32 + ((lane >> 4) << 3));
}
// A-fragment from bf16 LDS tile with row stride `str`. Rows >= NTOK clamp
// in-bounds; their results are discarded on store.
__device__ __forceinline__ short8v ldsA(const bf16* __restrict__ s, int str, int mt, int ks, int lane) {
    int row = mt*16 + (lane & 15);
    if (row >= NTOK) row = NTOK - 1;
    return *reinterpret_cast<const short8v*>(s + row*str + ks*32 + ((lane >> 4) << 3));
}

// ---- K0: one-shot fp32 -> bf16 weight conversion into d_ws ----
extern "C" __global__ __launch_bounds__(256)
void wconv(const float* __restrict__ Wp, const float* __restrict__ Wi,
           const float* __restrict__ Wo, bf16* __restrict__ ws) {
    int i = blockIdx.x*256 + threadIdx.x;     // 81920 total
    float v;
    if (i < 16384)      v = Wp[i];
    else if (i < 65536) v = Wi[i - 16384];
    else                v = Wo[i - 65536];
    ws[i] = __float2bfloat16(v);
}

extern "C" __global__ __launch_bounds__(NTHR, 8)
void bpa_fused(const float* __restrict__ h_joint,
               const float* __restrict__ mask_joint,
               const bf16* __restrict__ wgt,
               const float* __restrict__ b_proj, const float* __restrict__ b_in,
               const float* __restrict__ b_out,
               const float* __restrict__ ln_g,  const float* __restrict__ ln_b,
               float* __restrict__ out)
{
    __shared__ __align__(16) bf16 s_pool[NTOK*TSTR];   // pooled tokens; then v
    __shared__ __align__(16) bf16 s_tokp[NTOK*TSTR];   // proj out (A + residual)
    __shared__ __align__(16) bf16 s_qk[NTOK*QKSTR];    // q|k ; o over q; then y fp32
    __shared__ float s_probs[NG*NH*NP*NP];             // 2304 B
    __shared__ float s_mu[NTOK];
    __shared__ float s_inv[NTOK];
    float* s_y = reinterpret_cast<float*>(s_qk);       // [24][YSTR] fp32 (12.7KB <= 13.1KB)

    const int tid  = threadIdx.x;
    const int lane = tid & 63;
    const int w    = tid >> 6;                          // wave 0..7
    const long frame0 = (long)blockIdx.x * NG;

    // Prefetch W_proj B-fragments (tile w) — overlaps with pooling loads.
    short8v bp[4];
    #pragma unroll
    for (int ks = 0; ks < 4; ++ks) bp[ks] = ldB(wgt + WS_WP, w, ks, lane);

    // ---- Stage 1: pooling, fully unconditional & independent loads ----
    // thread -> (frame f = tid>>7, column d = tid&127). 17 coalesced h loads +
    // 17 broadcast mask loads; mask -> bitmask; joint->part reduce in regs.
    {
        const int f = tid >> 7;
        const int d = tid & (ND-1);
        const float* hcol = h_joint + (frame0 + f)*(long)(NJ*ND) + d;
        const float* mrow = mask_joint + (frame0 + f)*(long)NJ;

        float hv[NJ];
        #pragma unroll
        for (int j = 0; j < NJ; ++j) hv[j] = hcol[j*ND];      // independent
        unsigned mb = 0;
        #pragma unroll
        for (int j = 0; j < NJ; ++j)
            mb |= (mrow[j] > 0.05f) ? (1u << j) : 0u;          // independent
        #pragma unroll
        for (int j = 0; j < NJ; ++j)
            hv[j] = (mb >> j & 1) ? hv[j] : 0.f;

        float acc[NP];
        acc[0] = ((hv[0]+hv[1]) + (hv[2]+hv[3])) + hv[4];
        acc[1] = (hv[5]+hv[6]) + (hv[11]+hv[12]);
        acc[2] = hv[5]+hv[7]+hv[9];
        acc[3] = hv[6]+hv[8]+hv[10];
        acc[4] = hv[11]+hv[13]+hv[15];
        acc[5] = hv[12]+hv[14]+hv[16];
        const unsigned pm[NP] = {0x1Fu, 0x1860u, 0x2A0u, 0x540u, 0xA800u, 0x15000u};
        #pragma unroll
        for (int p = 0; p < NP; ++p) {
            float cnt = (float)__popc(mb & pm[p]);
            s_pool[(f*NP+p)*TSTR + d] = __float2bfloat16(acc[p] / fmaxf(cnt, 1e-6f));
        }
    }
    __syncthreads();

    // ---- Stage 2: proj = pool @ Wp^T + b  (wave w owns N-tile w) ----
    {
        f32x4 acc[NMT];
        acc[0] = (f32x4)(0.f); acc[1] = (f32x4)(0.f);
        #pragma unroll
        for (int ks = 0; ks < 4; ++ks)
            #pragma unroll
            for (int mt = 0; mt < NMT; ++mt)
                acc[mt] = MFMA(ldsA(s_pool, TSTR, mt, ks, lane), bp[ks], acc[mt]);
        int col = w*16 + (lane & 15);
        float bv = b_proj[col];
        #pragma unroll
        for (int mt = 0; mt < NMT; ++mt)
            #pragma unroll
            for (int j = 0; j < 4; ++j) {
                int row = mt*16 + ((lane >> 4) << 2) + j;
                if (row < NTOK)
                    s_tokp[row*TSTR + col] = __float2bfloat16(acc[mt][j] + bv);
            }
    }
    __syncthreads();

    // ---- Stage 3: qkv = tokp @ Win^T + b (wave w owns tiles w, 8+w, 16+w) ----
    #pragma unroll
    for (int t = 0; t < 3; ++t) {
        int nt = t*8 + w;                       // t=0:q, t=1:k, t=2:v
        short8v b[4];
        #pragma unroll
        for (int ks = 0; ks < 4; ++ks) b[ks] = ldB(wgt + WS_WI, nt, ks, lane);
        f32x4 acc[NMT];
        acc[0] = (f32x4)(0.f); acc[1] = (f32x4)(0.f);
        #pragma unroll
        for (int ks = 0; ks < 4; ++ks)
            #pragma unroll
            for (int mt = 0; mt < NMT; ++mt)
                acc[mt] = MFMA(ldsA(s_tokp, TSTR, mt, ks, lane), b[ks], acc[mt]);
        int col = nt*16 + (lane & 15);          // 0..383
        float bv = b_in[col];
        #pragma unroll
        for (int mt = 0; mt < NMT; ++mt)
            #pragma unroll
            for (int j = 0; j < 4; ++j) {
                int row = mt*16 + ((lane >> 4) << 2) + j;
                if (row < NTOK) {
                    float v = acc[mt][j] + bv;
                    if (t < 2) s_qk[row*QKSTR + col] = __float2bfloat16(v);
                    else       s_pool[row*TSTR + (col - 256)] = __float2bfloat16(v);
                }
            }
    }
    __syncthreads();

    // ---- Stage 4: attention scores + softmax -> s_probs ----
    if (tid < NG*NH*NP) {   // 96 threads: (f, h, qi)
        int f   = tid / (NH*NP);
        int rem = tid - f*(NH*NP);
        int h   = rem / NP;
        int qi  = rem - h*NP;
        const bf16* qrow = s_qk + (f*NP+qi)*QKSTR + h*NDH;
        float sc[NP];
        float mx = -1e30f;
        #pragma unroll
        for (int pk = 0; pk < NP; ++pk) {
            const bf16* krow = s_qk + (f*NP+pk)*QKSTR + ND + h*NDH;
            float s = 0.f;
            #pragma unroll
            for (int c = 0; c < NDH; c += 4) {
                ushort4 uq = *reinterpret_cast<const ushort4*>(qrow + c);
                ushort4 uk = *reinterpret_cast<const ushort4*>(krow + c);
                s += bf2f(uq.x)*bf2f(uk.x) + bf2f(uq.y)*bf2f(uk.y)
                   + bf2f(uq.z)*bf2f(uk.z) + bf2f(uq.w)*bf2f(uk.w);
            }
            sc[pk] = s * 0.17677669529663688f;   // 1/sqrt(32)
            mx = fmaxf(mx, sc[pk]);
        }
        float den = 0.f, e[NP];
        #pragma unroll
        for (int pk = 0; pk < NP; ++pk) { e[pk] = expf(sc[pk]-mx); den += e[pk]; }
        float inv = 1.f/den;
        #pragma unroll
        for (int pk = 0; pk < NP; ++pk)
            s_probs[((f*NH+h)*NP+qi)*NP + pk] = e[pk]*inv;
    }
    __syncthreads();

    // ---- Stage 5: part_importance + o = w @ v (o over q region of s_qk) ----
    if (tid < NG*NP) {  // 24 threads: (f, pk)
        int f = tid / NP, pk = tid - f*NP;
        float s = 0.f;
        #pragma unroll
        for (int h = 0; h < NH; ++h)
            #pragma unroll
            for (int q = 0; q < NP; ++q)
                s += s_probs[((f*NH+h)*NP+q)*NP + pk];
        out[(long)NBT*NP*ND + (frame0+f)*NP + pk] = s * (1.f/24.f);
    }
    #pragma unroll
    for (int i = 0; i < (NTOK*ND)/NTHR; ++i) {   // 6 iters
        int idx = i*NTHR + tid;
        int token = idx >> 7;
        int d = idx & (ND-1);
        int f = token / NP, qi = token - f*NP;
        int h = d >> 5;
        const float* pr = s_probs + ((f*NH+h)*NP+qi)*NP;
        float s = 0.f;
        #pragma unroll
        for (int pk = 0; pk < NP; ++pk) {
            float v = bf2f(reinterpret_cast<const unsigned short*>(s_pool)[(f*NP+pk)*TSTR + d]);
            s += pr[pk]*v;
        }
        s_qk[token*QKSTR + d] = __float2bfloat16(s);   // o over dead q
    }
    __syncthreads();

    // ---- Stage 6: y = o @ Wout^T + b + resid -> fp32 y (aliases s_qk) ----
    {
        short8v bo[4];
        #pragma unroll
        for (int ks = 0; ks < 4; ++ks) bo[ks] = ldB(wgt + WS_WO, w, ks, lane);
        f32x4 acc[NMT];
        acc[0] = (f32x4)(0.f); acc[1] = (f32x4)(0.f);
        #pragma unroll
        for (int ks = 0; ks < 4; ++ks)
            #pragma unroll
            for (int mt = 0; mt < NMT; ++mt)
                acc[mt] = MFMA(ldsA(s_qk, QKSTR, mt, ks, lane), bo[ks], acc[mt]);
        __syncthreads();   // all o reads done before y overwrites the region
        int col = w*16 + (lane & 15);
        float bv = b_out[col];
        #pragma unroll
        for (int mt = 0; mt < NMT; ++mt)
            #pragma unroll
            for (int j = 0; j < 4; ++j) {
                int row = mt*16 + ((lane >> 4) << 2) + j;
                if (row < NTOK) {
                    float resid = bf2f(*reinterpret_cast<const unsigned short*>(&s_tokp[row*TSTR + col]));
                    s_y[row*YSTR + col] = acc[mt][j] + bv + resid;
                }
            }
    }
    __syncthreads();

    // ---- Stage 7: LayerNorm stats (4 lanes per token) ----
    if (tid < NTOK*4) {   // 96 threads
        int token = tid >> 2, sub = tid & 3;
        const float* row = s_y + token*YSTR + sub*NDH;
        float s = 0.f, s2 = 0.f;
        #pragma unroll
        for (int j = 0; j < NDH; j += 4) {
            float4 v = *reinterpret_cast<const float4*>(row + j);
            s  += v.x + v.y + v.z + v.w;
            s2 += v.x*v.x + v.y*v.y + v.z*v.z + v.w*v.w;
        }
        s  += __shfl_xor(s, 1);  s  += __shfl_xor(s, 2);
        s2 += __shfl_xor(s2, 1); s2 += __shfl_xor(s2, 2);
        float mean = s * (1.f/128.f);
        float var  = s2 * (1.f/128.f) - mean*mean;
        if (sub == 0) {
            s_mu[token]  = mean;
            s_inv[token] = rsqrtf(var + 1e-5f);
        }
    }
    __syncthreads();

    // ---- Stage 8: normalize + coalesced store (768 float4, 512 threads) ----
    #pragma unroll
    for (int i = 0; i < 2; ++i) {
        int idx4 = i*NTHR + tid;
        if (idx4 < NTOK*(ND/4)) {
            int token = idx4 >> 5;
            int dj = (idx4 & 31) << 2;
            float mean = s_mu[token], inv = s_inv[token];
            float4 v = *reinterpret_cast<const float4*>(s_y + token*YSTR + dj);
            float4 g = *reinterpret_cast<const float4*>(ln_g + dj);
            float4 b = *reinterpret_cast<const float4*>(ln_b + dj);
            float4 r;
            r.x = (v.x-mean)*inv*g.x + b.x;
            r.y = (v.y-mean)*inv*g.y + b.y;
            r.z = (v.z-mean)*inv*g.z + b.z;
            r.w = (v.w-mean)*inv*g.w + b.w;
            *reinterpret_cast<float4*>(out + (frame0*NP + token)*(long)ND + dj) = r;
        }
    }
}

extern "C" void kernel_launch(void* const* d_in, const int* in_sizes, int n_in,
                              void* d_out, int out_size, void* d_ws, size_t ws_size,
                              hipStream_t stream) {
    const float* h_joint = (const float*)d_in[0];
    const float* mask    = (const float*)d_in[1];
    const float* W_proj  = (const float*)d_in[2];
    const float* b_proj  = (const float*)d_in[3];
    const float* W_in    = (const float*)d_in[4];
    const float* b_in    = (const float*)d_in[5];
    const float* W_out   = (const float*)d_in[6];
    const float* b_out   = (const float*)d_in[7];
    const float* ln_g    = (const float*)d_in[8];
    const float* ln_b    = (const float*)d_in[9];
    float* out = (float*)d_out;
    bf16* wgt = (bf16*)d_ws;                     // 81920 bf16 = 160 KB

    hipLaunchKernelGGL(wconv, dim3(81920/256), dim3(256), 0, stream,
                       W_proj, W_in, W_out, wgt);
    hipLaunchKernelGGL(bpa_fused, dim3(NBT/NG), dim3(NTHR), 0, stream,
                       h_joint, mask, wgt, b_proj, b_in, b_out, ln_g, ln_b, out);
}